// Round 10
// baseline (373.480 us; speedup 1.0000x reference)
//
#include <hip/hip_runtime.h>
#include <hip/hip_bf16.h>
#include <stdint.h>

// ---------------------------------------------------------------------------
// TripletAggregateUngated: B=2, N=256, W=128, H=8, D=16
//  K0: weight prep (validated): Wcat2[2][144][128] bf16 (ln_g folded),
//      WOt2, bcat (ln_b folded) via 288 parallel reduction blocks.
//  K1 (validated, 54.5 us): register-A-frag, single-pass LN, manual f2bf,
//      acc[4][2] halves, (256,3). BYTE-IDENTICAL to round-9 anchor.
//  K3 (round-13): 512-thread / 256x128-tile restructure. Per-wave inner
//      loop identical to validated k3 (aq[4]/bq[4]/acc[4][4], same swizzle);
//      changes: full-256-row A tile (B panel fetched ONCE, was 2x),
//      LDS 48 KB -> 3 blocks/CU x 8 waves = 24 waves/CU (was 12),
//      epilogue in two 128-row halves through the same 34-KB C buffer with
//      the same line-completing store discipline. Register budget at
//      (512,6) = ~341/wave >> ~119 peak -> the R1/R3/R4/R8 spill failure
//      mode is structurally excluded.
//  K4: validated round-0 form, (256,3).
// Closed levers: (256,4) on k1/k3/k4 (spill/regress R6/R7/R11); LN depth-2
// prefetch (neutral R9); inline-asm cvt_pk (regress R10); XCD pair-swizzle
// (regress R6).
// Rule R3/R5/R6: every global store pattern must complete 128-B lines within
// one wave's consecutive instructions.
// Spill tripwire: k1 hbm_bytes algorithmic = 1.49e8; >1.6e8 = spill.
// ---------------------------------------------------------------------------

typedef short short8 __attribute__((ext_vector_type(8)));
typedef short short4v __attribute__((ext_vector_type(4)));
typedef float floatx4 __attribute__((ext_vector_type(4)));

#define AS1(p) ((const __attribute__((address_space(1))) void*)(p))
#define AS3(p) ((__attribute__((address_space(3))) void*)(p))

__device__ inline short f2bf(float v) {
    uint32_t u = __builtin_bit_cast(uint32_t, v);
    u += 0x7FFFu + ((u >> 16) & 1u);   // RNE; inputs finite
    return (short)(u >> 16);
}

// ---------------------------------------------------------------------------
// K0: weight/bias prep. ln_g folded into Wcat2 rows, ln_b folded into bcat.
// bx <288: Wcat2; [288,320): WOt2; [320,608): bcat via parallel k-reduction.
// ---------------------------------------------------------------------------
__global__ __launch_bounds__(128) void k0_prep(const float* __restrict__ WV,
                                               const float* __restrict__ WE,
                                               const float* __restrict__ WO,
                                               const float* __restrict__ ln_g,
                                               const float* __restrict__ ln_b,
                                               short* __restrict__ Wcat2,
                                               short* __restrict__ WOt2,
                                               const float* __restrict__ bV,
                                               const float* __restrict__ bE,
                                               float* __restrict__ bcat) {
    int bx = blockIdx.x, t = threadIdx.x;
    if (bx < 288) {
        int v = bx / 144, n = bx % 144, k = t;
        float val = 0.f;
        if (n < 128) val = WV[k * 256 + v * 128 + n];
        else if (n < 136) val = WE[k * 16 + v * 8 + (n - 128)];
        Wcat2[(v * 144 + n) * 128 + k] = f2bf(val * ln_g[k]);
    } else if (bx < 320) {
        int cc = bx - 288;
        for (int j = 0; j < 8; ++j) {
            int c = cc * 8 + j;
            WOt2[(cc * 128 + t) * 8 + j] =
                f2bf(WO[((c & 15) * 16 + (c >> 4)) * 128 + t]);
        }
    } else {
        int idx = bx - 320;                 // 0..287
        int v = idx / 144, n = idx % 144;
        int k = t;                          // 0..127
        float base = 0.f, wk = 0.f;
        if (n < 128) {
            base = bV[v * 128 + n];
            wk = WV[k * 256 + v * 128 + n];
        } else if (n < 136) {
            base = bE[v * 8 + (n - 128)];
            wk = WE[k * 16 + v * 8 + (n - 128)];
        }
        float p = ln_b[k] * wk;
        p += __shfl_xor(p, 1);  p += __shfl_xor(p, 2);
        p += __shfl_xor(p, 4);  p += __shfl_xor(p, 8);
        p += __shfl_xor(p, 16); p += __shfl_xor(p, 32);
        __shared__ float partial[2];
        if ((t & 63) == 0) partial[t >> 6] = p;
        __syncthreads();
        if (t == 0) bcat[idx] = base + partial[0] + partial[1];
    }
}

// ---------------------------------------------------------------------------
// K1 (round-5 validated): fused LN + projection + softmax, register-A-frag.
// blockIdx: x = fixed row (256), y = b (2), z = variant v (2).
//  v=0: fix=i, k=r2 -> V_in + E_in softmax; v=1: fix=j, k=r1 -> V_out + E_out.
// Wave w owns k-rows [w*64, w*64+64). Lane (quad,ln_) normalizes row
// (w*64+mt*16+ln_), cols quad*8+kk*32 -> exactly its MFMA A-fragment data.
// Wv in LDS: granule slot (r,p) holds source granule p ^ (r&15).
// V-chunk GEMM done in two ntl-halves (acc[4][2]) to keep peak register
// pressure ~134 < 168-reg cap of launch_bounds(256,3).
// ---------------------------------------------------------------------------
__global__ __launch_bounds__(256, 3) void k1_ln_proj(
    const float* __restrict__ e, const float* __restrict__ ln_g,
    const float* __restrict__ ln_b, const float* __restrict__ mask,
    const short* __restrict__ Wcat2, const float* __restrict__ bcat,
    short* __restrict__ VinT, short* __restrict__ VoutT,
    short* __restrict__ Ain, short* __restrict__ AoutT) {
    (void)ln_g; (void)ln_b;           // folded into Wcat2/bcat by k0
    __shared__ short Wlds[144 * 128]; // 36,864 B, granule-swizzled
    __shared__ float maskb[256];
    __shared__ float redm[4][8];
    __shared__ float reds[4][8];

    const int tid = threadIdx.x;
    const int fix = blockIdx.x;
    const int b = blockIdx.y;
    const int v = blockIdx.z;
    const int estride = v ? 256 : 1;
    const size_t ebase = (size_t)b * 65536 + (size_t)fix * (v ? 1 : 256);
    const short* Wv = Wcat2 + v * 144 * 128;
    const float* bc = bcat + v * 144;
    short* Vdst = v ? VoutT : VinT;
    short* Adst = v ? AoutT : Ain;

    const int lane = tid & 63, w = tid >> 6;
    const int ln_ = lane & 15, quad = lane >> 4;

    // ---- stage Wv -> LDS (async, hides under LN's global loads) ----
#pragma unroll
    for (int it = 0; it < 9; ++it) {
        int gid = it * 256 + tid;          // 0..2303
        int r = gid >> 4, p = gid & 15;
        const short* src = Wv + (r * 16 + (p ^ (r & 15))) * 8;
        __builtin_amdgcn_global_load_lds(AS1(src), AS3(&Wlds[gid * 8]), 16, 0, 0);
    }

    maskb[tid] = mask[(size_t)b * 65536 + (v ? (size_t)tid * 256 + fix
                                             : (size_t)fix * 256 + tid)];

    // ---- LayerNorm straight into per-wave A fragments (no LDS) ----
    short8 a_frag[4][4];
#pragma unroll
    for (int mt = 0; mt < 4; ++mt) {
        int row = w * 64 + mt * 16 + ln_;
        const float* ep = e + (ebase + (size_t)row * estride) * 128 + quad * 8;
        float4 c0[4], c1[4];
        float s = 0.f, s2 = 0.f;
#pragma unroll
        for (int kk = 0; kk < 4; ++kk) {
            c0[kk] = *(const float4*)(ep + kk * 32);
            c1[kk] = *(const float4*)(ep + kk * 32 + 4);
            s += c0[kk].x + c0[kk].y + c0[kk].z + c0[kk].w +
                 c1[kk].x + c1[kk].y + c1[kk].z + c1[kk].w;
            s2 += c0[kk].x * c0[kk].x + c0[kk].y * c0[kk].y +
                  c0[kk].z * c0[kk].z + c0[kk].w * c0[kk].w +
                  c1[kk].x * c1[kk].x + c1[kk].y * c1[kk].y +
                  c1[kk].z * c1[kk].z + c1[kk].w * c1[kk].w;
        }
        // row-sum across the 4 quads (lane bits 4,5)
        s += __shfl_xor(s, 16); s2 += __shfl_xor(s2, 16);
        s += __shfl_xor(s, 32); s2 += __shfl_xor(s2, 32);
        float mean = s * 0.0078125f;
        float var = s2 * 0.0078125f - mean * mean;
        float rs = rsqrtf(var + 1e-5f);
#pragma unroll
        for (int kk = 0; kk < 4; ++kk) {
            short8 o;
            o[0] = f2bf((c0[kk].x - mean) * rs);
            o[1] = f2bf((c0[kk].y - mean) * rs);
            o[2] = f2bf((c0[kk].z - mean) * rs);
            o[3] = f2bf((c0[kk].w - mean) * rs);
            o[4] = f2bf((c1[kk].x - mean) * rs);
            o[5] = f2bf((c1[kk].y - mean) * rs);
            o[6] = f2bf((c1[kk].z - mean) * rs);
            o[7] = f2bf((c1[kk].w - mean) * rs);
            a_frag[mt][kk] = o;
        }
    }
    __syncthreads();   // Wv staged + maskb visible

    float vE[16];

    // ---- V chunks: wave w owns k-rows w*64..w*64+63 (4 m-subtiles) ----
#pragma unroll
    for (int chunk = 0; chunk < 2; ++chunk) {
#pragma unroll
        for (int half = 0; half < 2; ++half) {
            floatx4 acc[4][2] = {};
#pragma unroll
            for (int kk = 0; kk < 4; ++kk) {
                int ckb = kk * 4 + quad;
                short8 bq[2];
#pragma unroll
                for (int nl = 0; nl < 2; ++nl) {
                    int n = chunk * 64 + (half * 2 + nl) * 16 + ln_;
                    bq[nl] = *(const short8*)&Wlds[(n * 16 + (ckb ^ (n & 15))) * 8];
                }
#pragma unroll
                for (int mt = 0; mt < 4; ++mt)
#pragma unroll
                    for (int nl = 0; nl < 2; ++nl)
                        acc[mt][nl] = __builtin_amdgcn_mfma_f32_16x16x32_bf16(
                            a_frag[mt][kk], bq[nl], acc[mt][nl], 0, 0, 0);
            }
#pragma unroll
            for (int nl = 0; nl < 2; ++nl) {
                int ntl = half * 2 + nl;
                int c = chunk * 64 + ntl * 16 + ln_;
                float bias = bc[c];
                int d = c >> 3, hh = c & 7;
                size_t rowbase = (((size_t)(b * 8 + hh) * 256 + fix) * 16 + d) * 256;
#pragma unroll
                for (int mt = 0; mt < 4; ++mt) {
                    short4v o;
#pragma unroll
                    for (int r = 0; r < 4; ++r) o[r] = f2bf(acc[mt][nl][r] + bias);
                    *(short4v*)(Vdst + rowbase + w * 64 + mt * 16 + quad * 4) = o;
                }
            }
        }
    }

    // ---- E chunk: cols 128..143 (8 real + 8 pad) ----
    {
        floatx4 accE[4] = {};
#pragma unroll
        for (int kk = 0; kk < 4; ++kk) {
            int ckb = kk * 4 + quad;
            int n = 128 + ln_;
            short8 bq = *(const short8*)&Wlds[(n * 16 + (ckb ^ (n & 15))) * 8];
#pragma unroll
            for (int mt = 0; mt < 4; ++mt)
                accE[mt] = __builtin_amdgcn_mfma_f32_16x16x32_bf16(
                    a_frag[mt][kk], bq, accE[mt], 0, 0, 0);
        }
        float bias = bc[128 + ln_];
#pragma unroll
        for (int mt = 0; mt < 4; ++mt)
#pragma unroll
            for (int r = 0; r < 4; ++r) {
                int k = w * 64 + mt * 16 + quad * 4 + r;
                vE[mt * 4 + r] = accE[mt][r] + bias + maskb[k];
            }
    }

    // ---- softmax over the 16 k-values per (lane-col, wave) ----
    {
        float m = vE[0];
#pragma unroll
        for (int i = 1; i < 16; ++i) m = fmaxf(m, vE[i]);
        m = fmaxf(m, __shfl_xor(m, 16));
        m = fmaxf(m, __shfl_xor(m, 32));
        if (quad == 0 && ln_ < 8) redm[w][ln_] = m;
        __syncthreads();
        int hs = ln_ & 7;
        float bmax = fmaxf(fmaxf(redm[0][hs], redm[1][hs]),
                           fmaxf(redm[2][hs], redm[3][hs]));
        float p[16], s = 0.f;
#pragma unroll
        for (int i = 0; i < 16; ++i) { p[i] = __expf(vE[i] - bmax); s += p[i]; }
        s += __shfl_xor(s, 16);
        s += __shfl_xor(s, 32);
        if (quad == 0 && ln_ < 8) reds[w][ln_] = s;
        __syncthreads();
        float inv = 1.f / (reds[0][hs] + reds[1][hs] + reds[2][hs] + reds[3][hs]);
        if (ln_ < 8) {
            size_t rowbase = (size_t)(b * 8 + ln_) * 65536 + (size_t)fix * 256;
#pragma unroll
            for (int mt = 0; mt < 4; ++mt) {
                short4v o;
#pragma unroll
                for (int r = 0; r < 4; ++r) o[r] = f2bf(p[mt * 4 + r] * inv);
                *(short4v*)(Adst + rowbase + w * 64 + mt * 16 + quad * 4) = o;
            }
        }
    }
}

// ---------------------------------------------------------------------------
// K3 (round-13): per (b,h,part): C[i,jd] = sum_k A[i,k] V[jd,k].
// 512 threads (8 waves), 256x128 tile, BK=64 x4.
// grid (32 jd-tiles, 32 z). Wave w: m0=(w>>1)*64 (256-row A), n0=(w&1)*64.
// LDS: A granules [0,2048) = 256 rows x 8, B [2048,3072) = 128 rows x 8;
// 49,152 B -> 3 blocks/CU x 8 waves = 24 waves/CU.
// Per-wave K-loop identical to validated k3. Epilogue: two 128-row halves
// through a 128x136 C buffer, cooperative line-complete stores.
// ---------------------------------------------------------------------------
__global__ __launch_bounds__(512, 6) void k3_einsum(const short* __restrict__ Ain,
                                                    const short* __restrict__ AoutT,
                                                    const short* __restrict__ VinT,
                                                    const short* __restrict__ VoutT,
                                                    short* __restrict__ VaP2) {
    __shared__ short AB[24576];  // 49,152 B (epilogue reuses first 34,816 B)
    const int tid = threadIdx.x, lane = tid & 63, w = tid >> 6;
    const int jd0 = blockIdx.x * 128;
    const int z = blockIdx.y;
    const int b = z >> 4, part = (z >> 3) & 1, h = z & 7;

    const short* Abase = (part ? AoutT : Ain) + ((size_t)(b * 8 + h)) * 65536;
    const short* Bbase = (part ? VoutT : VinT) + ((size_t)(b * 8 + h)) * 1048576 + (size_t)jd0 * 256;

    const int ln_ = lane & 15, quad = lane >> 4;
    const int m0 = (w >> 1) * 64, n0 = (w & 1) * 64;
    floatx4 acc[4][4] = {};

    for (int kt = 0; kt < 4; ++kt) {
        if (kt) __syncthreads();
        for (int it = 0; it < 6; ++it) {
            int cid = it * 512 + tid;             // 0..3071
            int isB = cid >> 11;                  // granules >=2048 are B
            int lc = isB ? (cid - 2048) : cid;
            int r = lc >> 3;                      // A: 0..255, B: 0..127
            int ck = (lc & 7) ^ (r & 7);
            const short* g = (isB ? Bbase : Abase) + r * 256 + kt * 64 + ck * 8;
            __builtin_amdgcn_global_load_lds(AS1(g), AS3(&AB[cid * 8]), 16, 0, 0);
        }
        __syncthreads();

#pragma unroll
        for (int kk = 0; kk < 2; ++kk) {
            int ckb = kk * 4 + quad;
            short8 aq[4], bq[4];
#pragma unroll
            for (int t = 0; t < 4; ++t) {
                int r = m0 + t * 16 + ln_;        // 0..255
                aq[t] = *(const short8*)&AB[(r * 8 + (ckb ^ (r & 7))) * 8];
            }
#pragma unroll
            for (int t = 0; t < 4; ++t) {
                int r = n0 + t * 16 + ln_;        // 0..127
                bq[t] = *(const short8*)&AB[(2048 + r * 8 + (ckb ^ (r & 7))) * 8];
            }
#pragma unroll
            for (int mt = 0; mt < 4; ++mt)
#pragma unroll
                for (int nt = 0; nt < 4; ++nt)
                    acc[mt][nt] = __builtin_amdgcn_mfma_f32_16x16x32_bf16(aq[mt], bq[nt], acc[mt][nt], 0, 0, 0);
        }
    }

    // ---- epilogue: two 128-row halves through a 128x136 C buffer ----
    const int ph = part * 8 + h;
    const int j0 = jd0 >> 4;
    __syncthreads();   // all AB K-loop reads done
#pragma unroll
    for (int mh = 0; mh < 2; ++mh) {
        if (mh) __syncthreads();    // previous half's stores done
        if ((m0 >> 7) == mh) {      // waves owning rows [mh*128, mh*128+128)
            int il0 = m0 & 127;
#pragma unroll
            for (int mt = 0; mt < 4; ++mt)
#pragma unroll
                for (int nt = 0; nt < 4; ++nt)
#pragma unroll
                    for (int r = 0; r < 4; ++r) {
                        int il = il0 + mt * 16 + quad * 4 + r;
                        int jd = n0 + nt * 16 + ln_;
                        AB[il * 136 + jd] = f2bf(acc[mt][nt][r]);
                    }
        }
        __syncthreads();            // C half staged
#pragma unroll
        for (int pp = 0; pp < 2; ++pp) {
            int pid = pp * 512 + tid;      // 0..1023
            int il = pid >> 3, jl = pid & 7;
            size_t m = ((size_t)b * 256 + mh * 128 + il) * 256 + j0 + jl;
            short8 v0 = *(const short8*)&AB[il * 136 + jl * 16];
            short8 v1 = *(const short8*)&AB[il * 136 + jl * 16 + 8];
            short* dst = VaP2 + ((size_t)ph * 131072 + m) * 16;
            *(short8*)dst = v0;
            *(short8*)(dst + 8) = v1;
        }
    }
}

// ---------------------------------------------------------------------------
// K4: out[m][w] = sum_c A[m][c] * WOt2[cc][w][8] + bO[w].
// Wave owns m0=w*32 (2 m-subtiles) x FULL 128-w width (acc[2][8]) so each
// out row's 512 B is stored by one wave in 8 consecutive instructions.
// (256,3) validated.
// ---------------------------------------------------------------------------
__global__ __launch_bounds__(256, 3) void k4_proj(const short* __restrict__ VaP2,
                                                  const short* __restrict__ WOt2,
                                                  const float* __restrict__ bO,
                                                  float* __restrict__ out) {
    __shared__ short A_s[16384];  // 32 KB
    const int tid = threadIdx.x, lane = tid & 63, w = tid >> 6;
    const size_t m0g = (size_t)blockIdx.x * 128;
    const int ln_ = lane & 15, quad = lane >> 4;
    const int m0 = w * 32;
    floatx4 acc[2][8] = {};

    for (int kt = 0; kt < 2; ++kt) {
        if (kt) __syncthreads();
        for (int it = 0; it < 8; ++it) {
            int cid = w * 512 + it * 64 + lane;     // 0..2047
            int p = cid >> 8, rm = cid & 255, half = rm >> 7, m = rm & 127;
            const short* g = VaP2 + ((size_t)(kt * 8 + p) * 131072 + m0g + m) * 16 + half * 8;
            __builtin_amdgcn_global_load_lds(AS1(g), AS3(&A_s[cid * 8]), 16, 0, 0);
        }
        __syncthreads();

#pragma unroll
        for (int kk = 0; kk < 4; ++kk) {
            int ckb = kk * 4 + quad;
            int p = ckb >> 1, hf = ckb & 1;
            short8 aq[2], bq[8];
#pragma unroll
            for (int mt = 0; mt < 2; ++mt) {
                int m = m0 + mt * 16 + ln_;
                aq[mt] = *(const short8*)&A_s[p * 2048 + hf * 1024 + m * 8];
            }
#pragma unroll
            for (int nt = 0; nt < 8; ++nt) {
                int wr = nt * 16 + ln_;
                bq[nt] = *(const short8*)(WOt2 + ((kt * 16 + ckb) * 128 + wr) * 8);
            }
#pragma unroll
            for (int mt = 0; mt < 2; ++mt)
#pragma unroll
                for (int nt = 0; nt < 8; ++nt)
                    acc[mt][nt] = __builtin_amdgcn_mfma_f32_16x16x32_bf16(aq[mt], bq[nt], acc[mt][nt], 0, 0, 0);
        }
    }

    float bo[8];
#pragma unroll
    for (int nt = 0; nt < 8; ++nt) bo[nt] = bO[nt * 16 + ln_];

#pragma unroll
    for (int mt = 0; mt < 2; ++mt)
#pragma unroll
        for (int r = 0; r < 4; ++r) {
            size_t mb = m0g + m0 + mt * 16 + quad * 4 + r;
#pragma unroll
            for (int nt = 0; nt < 8; ++nt)
                out[mb * 128 + nt * 16 + ln_] = acc[mt][nt][r] + bo[nt];
        }
}

// ---------------------------------------------------------------------------
extern "C" void kernel_launch(void* const* d_in, const int* in_sizes, int n_in,
                              void* d_out, int out_size, void* d_ws, size_t ws_size,
                              hipStream_t stream) {
    (void)in_sizes; (void)n_in; (void)out_size; (void)ws_size;
    const float* e    = (const float*)d_in[0];
    const float* mask = (const float*)d_in[1];
    const float* ln_g = (const float*)d_in[2];
    const float* ln_b = (const float*)d_in[3];
    const float* W_V  = (const float*)d_in[4];
    const float* b_V  = (const float*)d_in[5];
    const float* W_E  = (const float*)d_in[6];
    const float* b_E  = (const float*)d_in[7];
    const float* W_O  = (const float*)d_in[8];
    const float* b_O  = (const float*)d_in[9];
    float* out = (float*)d_out;

    char* ws = (char*)d_ws;
    short* VinT  = (short*)(ws + 0);           //  33,554,432 B
    short* VoutT = (short*)(ws + 33554432);    //  33,554,432 B
    short* Ain   = (short*)(ws + 67108864);    //   2,097,152 B
    short* AoutT = (short*)(ws + 69206016);    //   2,097,152 B
    short* VaP2  = (short*)(ws + 71303168);    //  67,108,864 B
    short* Wcat2 = (short*)(ws + 138412032);   //      73,728 B
    short* WOt2  = (short*)(ws + 138485760);   //      65,536 B
    float* bcat  = (float*)(ws + 138551296);   //       1,152 B

    k0_prep<<<608, 128, 0, stream>>>(W_V, W_E, W_O, ln_g, ln_b, Wcat2, WOt2,
                                     b_V, b_E, bcat);
    k1_ln_proj<<<dim3(256, 2, 2), 256, 0, stream>>>(e, ln_g, ln_b, mask, Wcat2,
                                                    bcat, VinT, VoutT, Ain, AoutT);
    k3_einsum<<<dim3(32, 32), 512, 0, stream>>>(Ain, AoutT, VinT, VoutT, VaP2);
    k4_proj<<<1024, 256, 0, stream>>>(VaP2, WOt2, b_O, out);
}

// Round 11
// 218.140 us; speedup vs baseline: 1.7121x; 1.7121x over previous
//
#include <hip/hip_runtime.h>
#include <hip/hip_bf16.h>
#include <stdint.h>

// ---------------------------------------------------------------------------
// TripletAggregateUngated: B=2, N=256, W=128, H=8, D=16
//  K0: weight prep (validated): Wcat2[2][144][128] bf16 (ln_g folded),
//      WOt2, bcat (ln_b folded) via 288 parallel reduction blocks.
//  K1 (validated, 54.5 us): register-A-frag, single-pass LN, manual f2bf,
//      acc[4][2] halves, (256,3). BYTE-IDENTICAL to round-9 anchor.
//  K3 (round-14): 512-thread / 256x128-tile, launch_bounds FIXED (512,4).
//      R13 post-mortem: pool is 512 regs/SIMD (confirmed 2x: R4 cap
//      168=512/3; R13 spill at (512,6)=85/wave vs ~106 needed -> 7.0e8
//      hbm_bytes of scratch traffic, k3=186us). (512,4) -> 128/wave ->
//      64 VGPR / 64 AGPR split: VGPR side aq16+bq16+addr~10=42 <= 64,
//      AGPR acc[4][4]=64 <= 64 -> spill structurally excluded.
//      2 blocks/CU x 8 waves = 16 waves/CU (vs 12 validated). B panel
//      fetched ONCE. R13 showed the structure delivers 3.8+ TB/s when
//      waves are resident; this removes the spill that wasted it.
//  K4: validated round-0 form, (256,3).
// Closed levers: (256,4) on k1 (spill R6/R7) and old-k3/k4 (R11 regress);
// LN depth-2 prefetch (neutral R9); inline-asm cvt_pk (regress R10); XCD
// pair-swizzle (regress R6).
// Rule R3/R5/R6: every global store pattern must complete 128-B lines within
// one wave's consecutive instructions.
// Rule R13: unified reg pool = 512/SIMD. Budget/wave = 512/(waves per SIMD).
// Spill tripwire: k1 algorithmic = 1.49e8; k3 algorithmic ~2e8 with
// write-allocate; anything >3e8 on k3 = spill/thrash.
// ---------------------------------------------------------------------------

typedef short short8 __attribute__((ext_vector_type(8)));
typedef short short4v __attribute__((ext_vector_type(4)));
typedef float floatx4 __attribute__((ext_vector_type(4)));

#define AS1(p) ((const __attribute__((address_space(1))) void*)(p))
#define AS3(p) ((__attribute__((address_space(3))) void*)(p))

__device__ inline short f2bf(float v) {
    uint32_t u = __builtin_bit_cast(uint32_t, v);
    u += 0x7FFFu + ((u >> 16) & 1u);   // RNE; inputs finite
    return (short)(u >> 16);
}

// ---------------------------------------------------------------------------
// K0: weight/bias prep. ln_g folded into Wcat2 rows, ln_b folded into bcat.
// bx <288: Wcat2; [288,320): WOt2; [320,608): bcat via parallel k-reduction.
// ---------------------------------------------------------------------------
__global__ __launch_bounds__(128) void k0_prep(const float* __restrict__ WV,
                                               const float* __restrict__ WE,
                                               const float* __restrict__ WO,
                                               const float* __restrict__ ln_g,
                                               const float* __restrict__ ln_b,
                                               short* __restrict__ Wcat2,
                                               short* __restrict__ WOt2,
                                               const float* __restrict__ bV,
                                               const float* __restrict__ bE,
                                               float* __restrict__ bcat) {
    int bx = blockIdx.x, t = threadIdx.x;
    if (bx < 288) {
        int v = bx / 144, n = bx % 144, k = t;
        float val = 0.f;
        if (n < 128) val = WV[k * 256 + v * 128 + n];
        else if (n < 136) val = WE[k * 16 + v * 8 + (n - 128)];
        Wcat2[(v * 144 + n) * 128 + k] = f2bf(val * ln_g[k]);
    } else if (bx < 320) {
        int cc = bx - 288;
        for (int j = 0; j < 8; ++j) {
            int c = cc * 8 + j;
            WOt2[(cc * 128 + t) * 8 + j] =
                f2bf(WO[((c & 15) * 16 + (c >> 4)) * 128 + t]);
        }
    } else {
        int idx = bx - 320;                 // 0..287
        int v = idx / 144, n = idx % 144;
        int k = t;                          // 0..127
        float base = 0.f, wk = 0.f;
        if (n < 128) {
            base = bV[v * 128 + n];
            wk = WV[k * 256 + v * 128 + n];
        } else if (n < 136) {
            base = bE[v * 8 + (n - 128)];
            wk = WE[k * 16 + v * 8 + (n - 128)];
        }
        float p = ln_b[k] * wk;
        p += __shfl_xor(p, 1);  p += __shfl_xor(p, 2);
        p += __shfl_xor(p, 4);  p += __shfl_xor(p, 8);
        p += __shfl_xor(p, 16); p += __shfl_xor(p, 32);
        __shared__ float partial[2];
        if ((t & 63) == 0) partial[t >> 6] = p;
        __syncthreads();
        if (t == 0) bcat[idx] = base + partial[0] + partial[1];
    }
}

// ---------------------------------------------------------------------------
// K1 (round-5 validated): fused LN + projection + softmax, register-A-frag.
// blockIdx: x = fixed row (256), y = b (2), z = variant v (2).
//  v=0: fix=i, k=r2 -> V_in + E_in softmax; v=1: fix=j, k=r1 -> V_out + E_out.
// Wave w owns k-rows [w*64, w*64+64). Lane (quad,ln_) normalizes row
// (w*64+mt*16+ln_), cols quad*8+kk*32 -> exactly its MFMA A-fragment data.
// Wv in LDS: granule slot (r,p) holds source granule p ^ (r&15).
// V-chunk GEMM done in two ntl-halves (acc[4][2]) to keep peak register
// pressure ~134 < 168-reg cap of launch_bounds(256,3).
// ---------------------------------------------------------------------------
__global__ __launch_bounds__(256, 3) void k1_ln_proj(
    const float* __restrict__ e, const float* __restrict__ ln_g,
    const float* __restrict__ ln_b, const float* __restrict__ mask,
    const short* __restrict__ Wcat2, const float* __restrict__ bcat,
    short* __restrict__ VinT, short* __restrict__ VoutT,
    short* __restrict__ Ain, short* __restrict__ AoutT) {
    (void)ln_g; (void)ln_b;           // folded into Wcat2/bcat by k0
    __shared__ short Wlds[144 * 128]; // 36,864 B, granule-swizzled
    __shared__ float maskb[256];
    __shared__ float redm[4][8];
    __shared__ float reds[4][8];

    const int tid = threadIdx.x;
    const int fix = blockIdx.x;
    const int b = blockIdx.y;
    const int v = blockIdx.z;
    const int estride = v ? 256 : 1;
    const size_t ebase = (size_t)b * 65536 + (size_t)fix * (v ? 1 : 256);
    const short* Wv = Wcat2 + v * 144 * 128;
    const float* bc = bcat + v * 144;
    short* Vdst = v ? VoutT : VinT;
    short* Adst = v ? AoutT : Ain;

    const int lane = tid & 63, w = tid >> 6;
    const int ln_ = lane & 15, quad = lane >> 4;

    // ---- stage Wv -> LDS (async, hides under LN's global loads) ----
#pragma unroll
    for (int it = 0; it < 9; ++it) {
        int gid = it * 256 + tid;          // 0..2303
        int r = gid >> 4, p = gid & 15;
        const short* src = Wv + (r * 16 + (p ^ (r & 15))) * 8;
        __builtin_amdgcn_global_load_lds(AS1(src), AS3(&Wlds[gid * 8]), 16, 0, 0);
    }

    maskb[tid] = mask[(size_t)b * 65536 + (v ? (size_t)tid * 256 + fix
                                             : (size_t)fix * 256 + tid)];

    // ---- LayerNorm straight into per-wave A fragments (no LDS) ----
    short8 a_frag[4][4];
#pragma unroll
    for (int mt = 0; mt < 4; ++mt) {
        int row = w * 64 + mt * 16 + ln_;
        const float* ep = e + (ebase + (size_t)row * estride) * 128 + quad * 8;
        float4 c0[4], c1[4];
        float s = 0.f, s2 = 0.f;
#pragma unroll
        for (int kk = 0; kk < 4; ++kk) {
            c0[kk] = *(const float4*)(ep + kk * 32);
            c1[kk] = *(const float4*)(ep + kk * 32 + 4);
            s += c0[kk].x + c0[kk].y + c0[kk].z + c0[kk].w +
                 c1[kk].x + c1[kk].y + c1[kk].z + c1[kk].w;
            s2 += c0[kk].x * c0[kk].x + c0[kk].y * c0[kk].y +
                  c0[kk].z * c0[kk].z + c0[kk].w * c0[kk].w +
                  c1[kk].x * c1[kk].x + c1[kk].y * c1[kk].y +
                  c1[kk].z * c1[kk].z + c1[kk].w * c1[kk].w;
        }
        // row-sum across the 4 quads (lane bits 4,5)
        s += __shfl_xor(s, 16); s2 += __shfl_xor(s2, 16);
        s += __shfl_xor(s, 32); s2 += __shfl_xor(s2, 32);
        float mean = s * 0.0078125f;
        float var = s2 * 0.0078125f - mean * mean;
        float rs = rsqrtf(var + 1e-5f);
#pragma unroll
        for (int kk = 0; kk < 4; ++kk) {
            short8 o;
            o[0] = f2bf((c0[kk].x - mean) * rs);
            o[1] = f2bf((c0[kk].y - mean) * rs);
            o[2] = f2bf((c0[kk].z - mean) * rs);
            o[3] = f2bf((c0[kk].w - mean) * rs);
            o[4] = f2bf((c1[kk].x - mean) * rs);
            o[5] = f2bf((c1[kk].y - mean) * rs);
            o[6] = f2bf((c1[kk].z - mean) * rs);
            o[7] = f2bf((c1[kk].w - mean) * rs);
            a_frag[mt][kk] = o;
        }
    }
    __syncthreads();   // Wv staged + maskb visible

    float vE[16];

    // ---- V chunks: wave w owns k-rows w*64..w*64+63 (4 m-subtiles) ----
#pragma unroll
    for (int chunk = 0; chunk < 2; ++chunk) {
#pragma unroll
        for (int half = 0; half < 2; ++half) {
            floatx4 acc[4][2] = {};
#pragma unroll
            for (int kk = 0; kk < 4; ++kk) {
                int ckb = kk * 4 + quad;
                short8 bq[2];
#pragma unroll
                for (int nl = 0; nl < 2; ++nl) {
                    int n = chunk * 64 + (half * 2 + nl) * 16 + ln_;
                    bq[nl] = *(const short8*)&Wlds[(n * 16 + (ckb ^ (n & 15))) * 8];
                }
#pragma unroll
                for (int mt = 0; mt < 4; ++mt)
#pragma unroll
                    for (int nl = 0; nl < 2; ++nl)
                        acc[mt][nl] = __builtin_amdgcn_mfma_f32_16x16x32_bf16(
                            a_frag[mt][kk], bq[nl], acc[mt][nl], 0, 0, 0);
            }
#pragma unroll
            for (int nl = 0; nl < 2; ++nl) {
                int ntl = half * 2 + nl;
                int c = chunk * 64 + ntl * 16 + ln_;
                float bias = bc[c];
                int d = c >> 3, hh = c & 7;
                size_t rowbase = (((size_t)(b * 8 + hh) * 256 + fix) * 16 + d) * 256;
#pragma unroll
                for (int mt = 0; mt < 4; ++mt) {
                    short4v o;
#pragma unroll
                    for (int r = 0; r < 4; ++r) o[r] = f2bf(acc[mt][nl][r] + bias);
                    *(short4v*)(Vdst + rowbase + w * 64 + mt * 16 + quad * 4) = o;
                }
            }
        }
    }

    // ---- E chunk: cols 128..143 (8 real + 8 pad) ----
    {
        floatx4 accE[4] = {};
#pragma unroll
        for (int kk = 0; kk < 4; ++kk) {
            int ckb = kk * 4 + quad;
            int n = 128 + ln_;
            short8 bq = *(const short8*)&Wlds[(n * 16 + (ckb ^ (n & 15))) * 8];
#pragma unroll
            for (int mt = 0; mt < 4; ++mt)
                accE[mt] = __builtin_amdgcn_mfma_f32_16x16x32_bf16(
                    a_frag[mt][kk], bq, accE[mt], 0, 0, 0);
        }
        float bias = bc[128 + ln_];
#pragma unroll
        for (int mt = 0; mt < 4; ++mt)
#pragma unroll
            for (int r = 0; r < 4; ++r) {
                int k = w * 64 + mt * 16 + quad * 4 + r;
                vE[mt * 4 + r] = accE[mt][r] + bias + maskb[k];
            }
    }

    // ---- softmax over the 16 k-values per (lane-col, wave) ----
    {
        float m = vE[0];
#pragma unroll
        for (int i = 1; i < 16; ++i) m = fmaxf(m, vE[i]);
        m = fmaxf(m, __shfl_xor(m, 16));
        m = fmaxf(m, __shfl_xor(m, 32));
        if (quad == 0 && ln_ < 8) redm[w][ln_] = m;
        __syncthreads();
        int hs = ln_ & 7;
        float bmax = fmaxf(fmaxf(redm[0][hs], redm[1][hs]),
                           fmaxf(redm[2][hs], redm[3][hs]));
        float p[16], s = 0.f;
#pragma unroll
        for (int i = 0; i < 16; ++i) { p[i] = __expf(vE[i] - bmax); s += p[i]; }
        s += __shfl_xor(s, 16);
        s += __shfl_xor(s, 32);
        if (quad == 0 && ln_ < 8) reds[w][ln_] = s;
        __syncthreads();
        float inv = 1.f / (reds[0][hs] + reds[1][hs] + reds[2][hs] + reds[3][hs]);
        if (ln_ < 8) {
            size_t rowbase = (size_t)(b * 8 + ln_) * 65536 + (size_t)fix * 256;
#pragma unroll
            for (int mt = 0; mt < 4; ++mt) {
                short4v o;
#pragma unroll
                for (int r = 0; r < 4; ++r) o[r] = f2bf(p[mt * 4 + r] * inv);
                *(short4v*)(Adst + rowbase + w * 64 + mt * 16 + quad * 4) = o;
            }
        }
    }
}

// ---------------------------------------------------------------------------
// K3 (round-14): per (b,h,part): C[i,jd] = sum_k A[i,k] V[jd,k].
// 512 threads (8 waves), 256x128 tile, BK=64 x4, launch_bounds (512,4):
// 4 waves/SIMD -> 128 regs/wave -> 64 VGPR / 64 AGPR split; VGPR side
// aq16+bq16+addr~10=42 <= 64, AGPR acc=64 <= 64 -> no spill (R13 fix).
// 2 blocks/CU x 8 waves = 16 waves/CU. LDS 49,152 B x 2 = 98 KB.
// grid (32 jd-tiles, 32 z). Wave w: m0=(w>>1)*64 (256-row A), n0=(w&1)*64.
// B panel fetched ONCE (A re-reads L2/L3-served).
// Epilogue: two 128-row halves through a 128x136 C buffer, cooperative
// line-complete stores.
// ---------------------------------------------------------------------------
__global__ __launch_bounds__(512, 4) void k3_einsum(const short* __restrict__ Ain,
                                                    const short* __restrict__ AoutT,
                                                    const short* __restrict__ VinT,
                                                    const short* __restrict__ VoutT,
                                                    short* __restrict__ VaP2) {
    __shared__ short AB[24576];  // 49,152 B (epilogue reuses first 34,816 B)
    const int tid = threadIdx.x, lane = tid & 63, w = tid >> 6;
    const int jd0 = blockIdx.x * 128;
    const int z = blockIdx.y;
    const int b = z >> 4, part = (z >> 3) & 1, h = z & 7;

    const short* Abase = (part ? AoutT : Ain) + ((size_t)(b * 8 + h)) * 65536;
    const short* Bbase = (part ? VoutT : VinT) + ((size_t)(b * 8 + h)) * 1048576 + (size_t)jd0 * 256;

    const int ln_ = lane & 15, quad = lane >> 4;
    const int m0 = (w >> 1) * 64, n0 = (w & 1) * 64;
    floatx4 acc[4][4] = {};

    for (int kt = 0; kt < 4; ++kt) {
        if (kt) __syncthreads();
        for (int it = 0; it < 6; ++it) {
            int cid = it * 512 + tid;             // 0..3071
            int isB = cid >> 11;                  // granules >=2048 are B
            int lc = isB ? (cid - 2048) : cid;
            int r = lc >> 3;                      // A: 0..255, B: 0..127
            int ck = (lc & 7) ^ (r & 7);
            const short* g = (isB ? Bbase : Abase) + r * 256 + kt * 64 + ck * 8;
            __builtin_amdgcn_global_load_lds(AS1(g), AS3(&AB[cid * 8]), 16, 0, 0);
        }
        __syncthreads();

#pragma unroll
        for (int kk = 0; kk < 2; ++kk) {
            int ckb = kk * 4 + quad;
            short8 aq[4], bq[4];
#pragma unroll
            for (int t = 0; t < 4; ++t) {
                int r = m0 + t * 16 + ln_;        // 0..255
                aq[t] = *(const short8*)&AB[(r * 8 + (ckb ^ (r & 7))) * 8];
            }
#pragma unroll
            for (int t = 0; t < 4; ++t) {
                int r = n0 + t * 16 + ln_;        // 0..127
                bq[t] = *(const short8*)&AB[(2048 + r * 8 + (ckb ^ (r & 7))) * 8];
            }
#pragma unroll
            for (int mt = 0; mt < 4; ++mt)
#pragma unroll
                for (int nt = 0; nt < 4; ++nt)
                    acc[mt][nt] = __builtin_amdgcn_mfma_f32_16x16x32_bf16(aq[mt], bq[nt], acc[mt][nt], 0, 0, 0);
        }
    }

    // ---- epilogue: two 128-row halves through a 128x136 C buffer ----
    const int ph = part * 8 + h;
    const int j0 = jd0 >> 4;
    __syncthreads();   // all AB K-loop reads done
#pragma unroll
    for (int mh = 0; mh < 2; ++mh) {
        if (mh) __syncthreads();    // previous half's stores done
        if ((m0 >> 7) == mh) {      // waves owning rows [mh*128, mh*128+128)
            int il0 = m0 & 127;
#pragma unroll
            for (int mt = 0; mt < 4; ++mt)
#pragma unroll
                for (int nt = 0; nt < 4; ++nt)
#pragma unroll
                    for (int r = 0; r < 4; ++r) {
                        int il = il0 + mt * 16 + quad * 4 + r;
                        int jd = n0 + nt * 16 + ln_;
                        AB[il * 136 + jd] = f2bf(acc[mt][nt][r]);
                    }
        }
        __syncthreads();            // C half staged
#pragma unroll
        for (int pp = 0; pp < 2; ++pp) {
            int pid = pp * 512 + tid;      // 0..1023
            int il = pid >> 3, jl = pid & 7;
            size_t m = ((size_t)b * 256 + mh * 128 + il) * 256 + j0 + jl;
            short8 v0 = *(const short8*)&AB[il * 136 + jl * 16];
            short8 v1 = *(const short8*)&AB[il * 136 + jl * 16 + 8];
            short* dst = VaP2 + ((size_t)ph * 131072 + m) * 16;
            *(short8*)dst = v0;
            *(short8*)(dst + 8) = v1;
        }
    }
}

// ---------------------------------------------------------------------------
// K4: out[m][w] = sum_c A[m][c] * WOt2[cc][w][8] + bO[w].
// Wave owns m0=w*32 (2 m-subtiles) x FULL 128-w width (acc[2][8]) so each
// out row's 512 B is stored by one wave in 8 consecutive instructions.
// (256,3) validated.
// ---------------------------------------------------------------------------
__global__ __launch_bounds__(256, 3) void k4_proj(const short* __restrict__ VaP2,
                                                  const short* __restrict__ WOt2,
                                                  const float* __restrict__ bO,
                                                  float* __restrict__ out) {
    __shared__ short A_s[16384];  // 32 KB
    const int tid = threadIdx.x, lane = tid & 63, w = tid >> 6;
    const size_t m0g = (size_t)blockIdx.x * 128;
    const int ln_ = lane & 15, quad = lane >> 4;
    const int m0 = w * 32;
    floatx4 acc[2][8] = {};

    for (int kt = 0; kt < 2; ++kt) {
        if (kt) __syncthreads();
        for (int it = 0; it < 8; ++it) {
            int cid = w * 512 + it * 64 + lane;     // 0..2047
            int p = cid >> 8, rm = cid & 255, half = rm >> 7, m = rm & 127;
            const short* g = VaP2 + ((size_t)(kt * 8 + p) * 131072 + m0g + m) * 16 + half * 8;
            __builtin_amdgcn_global_load_lds(AS1(g), AS3(&A_s[cid * 8]), 16, 0, 0);
        }
        __syncthreads();

#pragma unroll
        for (int kk = 0; kk < 4; ++kk) {
            int ckb = kk * 4 + quad;
            int p = ckb >> 1, hf = ckb & 1;
            short8 aq[2], bq[8];
#pragma unroll
            for (int mt = 0; mt < 2; ++mt) {
                int m = m0 + mt * 16 + ln_;
                aq[mt] = *(const short8*)&A_s[p * 2048 + hf * 1024 + m * 8];
            }
#pragma unroll
            for (int nt = 0; nt < 8; ++nt) {
                int wr = nt * 16 + ln_;
                bq[nt] = *(const short8*)(WOt2 + ((kt * 16 + ckb) * 128 + wr) * 8);
            }
#pragma unroll
            for (int mt = 0; mt < 2; ++mt)
#pragma unroll
                for (int nt = 0; nt < 8; ++nt)
                    acc[mt][nt] = __builtin_amdgcn_mfma_f32_16x16x32_bf16(aq[mt], bq[nt], acc[mt][nt], 0, 0, 0);
        }
    }

    float bo[8];
#pragma unroll
    for (int nt = 0; nt < 8; ++nt) bo[nt] = bO[nt * 16 + ln_];

#pragma unroll
    for (int mt = 0; mt < 2; ++mt)
#pragma unroll
        for (int r = 0; r < 4; ++r) {
            size_t mb = m0g + m0 + mt * 16 + quad * 4 + r;
#pragma unroll
            for (int nt = 0; nt < 8; ++nt)
                out[mb * 128 + nt * 16 + ln_] = acc[mt][nt][r] + bo[nt];
        }
}

// ---------------------------------------------------------------------------
extern "C" void kernel_launch(void* const* d_in, const int* in_sizes, int n_in,
                              void* d_out, int out_size, void* d_ws, size_t ws_size,
                              hipStream_t stream) {
    (void)in_sizes; (void)n_in; (void)out_size; (void)ws_size;
    const float* e    = (const float*)d_in[0];
    const float* mask = (const float*)d_in[1];
    const float* ln_g = (const float*)d_in[2];
    const float* ln_b = (const float*)d_in[3];
    const float* W_V  = (const float*)d_in[4];
    const float* b_V  = (const float*)d_in[5];
    const float* W_E  = (const float*)d_in[6];
    const float* b_E  = (const float*)d_in[7];
    const float* W_O  = (const float*)d_in[8];
    const float* b_O  = (const float*)d_in[9];
    float* out = (float*)d_out;

    char* ws = (char*)d_ws;
    short* VinT  = (short*)(ws + 0);           //  33,554,432 B
    short* VoutT = (short*)(ws + 33554432);    //  33,554,432 B
    short* Ain   = (short*)(ws + 67108864);    //   2,097,152 B
    short* AoutT = (short*)(ws + 69206016);    //   2,097,152 B
    short* VaP2  = (short*)(ws + 71303168);    //  67,108,864 B
    short* Wcat2 = (short*)(ws + 138412032);   //      73,728 B
    short* WOt2  = (short*)(ws + 138485760);   //      65,536 B
    float* bcat  = (float*)(ws + 138551296);   //       1,152 B

    k0_prep<<<608, 128, 0, stream>>>(W_V, W_E, W_O, ln_g, ln_b, Wcat2, WOt2,
                                     b_V, b_E, bcat);
    k1_ln_proj<<<dim3(256, 2, 2), 256, 0, stream>>>(e, ln_g, ln_b, mask, Wcat2,
                                                    bcat, VinT, VoutT, Ain, AoutT);
    k3_einsum<<<dim3(32, 32), 512, 0, stream>>>(Ain, AoutT, VinT, VoutT, VaP2);
    k4_proj<<<1024, 256, 0, stream>>>(VaP2, WOt2, b_O, out);
}

// Round 12
// 217.759 us; speedup vs baseline: 1.7151x; 1.0017x over previous
//
#include <hip/hip_runtime.h>
#include <hip/hip_bf16.h>
#include <stdint.h>

// ---------------------------------------------------------------------------
// TripletAggregateUngated: B=2, N=256, W=128, H=8, D=16
//  K0: weight prep (validated): Wcat2[2][144][128] bf16 (ln_g folded),
//      WOt2, bcat (ln_b folded) via 288 parallel reduction blocks.
//  K1 (validated, 54.5 us): register-A-frag, single-pass LN, manual f2bf,
//      acc[4][2] halves, (256,3). BYTE-IDENTICAL to round-9 anchor.
//  K3 (validated round-14): 512-thread / 256x128-tile, (512,4) ->
//      64 VGPR / 64 AGPR split, no spill, 16 waves/CU. Session best 218.1.
//      (R14 lesson: B panels L3-fit, so B-once saved HBM little; the win
//      is residency.)
//  K4 (round-15): same (512,4) transformation applied to k4: 512 threads,
//      256-row tile, A_s 64 KB (2 blocks/CU -> 128 KB LDS, 16 waves/CU).
//      Per-wave inner loop byte-identical (m0=w*32, same aq/bq/MFMA/store
//      formulas); staging decode widened one bit; grid 512.
//      VGPR side aq8+bq32+bo8+addr~10 <= 64, acc[2][8]=64 AGPR -> no spill.
// Closed levers: (256,4) on k1 (spill); LN depth-2 prefetch (neutral);
// inline-asm cvt_pk (regress); XCD pair-swizzle (regress).
// Rule R3/R5/R6: every global store pattern must complete 128-B lines within
// one wave's consecutive instructions.
// Rule R13: unified reg pool = 512/SIMD. Budget/wave = 512/(waves per SIMD).
// Spill tripwires: k1 algorithmic = 1.49e8; k4 in top-5 with VGPR~40 +
// WRITE_SIZE inflation = spill -> revert.
// ---------------------------------------------------------------------------

typedef short short8 __attribute__((ext_vector_type(8)));
typedef short short4v __attribute__((ext_vector_type(4)));
typedef float floatx4 __attribute__((ext_vector_type(4)));

#define AS1(p) ((const __attribute__((address_space(1))) void*)(p))
#define AS3(p) ((__attribute__((address_space(3))) void*)(p))

__device__ inline short f2bf(float v) {
    uint32_t u = __builtin_bit_cast(uint32_t, v);
    u += 0x7FFFu + ((u >> 16) & 1u);   // RNE; inputs finite
    return (short)(u >> 16);
}

// ---------------------------------------------------------------------------
// K0: weight/bias prep. ln_g folded into Wcat2 rows, ln_b folded into bcat.
// bx <288: Wcat2; [288,320): WOt2; [320,608): bcat via parallel k-reduction.
// ---------------------------------------------------------------------------
__global__ __launch_bounds__(128) void k0_prep(const float* __restrict__ WV,
                                               const float* __restrict__ WE,
                                               const float* __restrict__ WO,
                                               const float* __restrict__ ln_g,
                                               const float* __restrict__ ln_b,
                                               short* __restrict__ Wcat2,
                                               short* __restrict__ WOt2,
                                               const float* __restrict__ bV,
                                               const float* __restrict__ bE,
                                               float* __restrict__ bcat) {
    int bx = blockIdx.x, t = threadIdx.x;
    if (bx < 288) {
        int v = bx / 144, n = bx % 144, k = t;
        float val = 0.f;
        if (n < 128) val = WV[k * 256 + v * 128 + n];
        else if (n < 136) val = WE[k * 16 + v * 8 + (n - 128)];
        Wcat2[(v * 144 + n) * 128 + k] = f2bf(val * ln_g[k]);
    } else if (bx < 320) {
        int cc = bx - 288;
        for (int j = 0; j < 8; ++j) {
            int c = cc * 8 + j;
            WOt2[(cc * 128 + t) * 8 + j] =
                f2bf(WO[((c & 15) * 16 + (c >> 4)) * 128 + t]);
        }
    } else {
        int idx = bx - 320;                 // 0..287
        int v = idx / 144, n = idx % 144;
        int k = t;                          // 0..127
        float base = 0.f, wk = 0.f;
        if (n < 128) {
            base = bV[v * 128 + n];
            wk = WV[k * 256 + v * 128 + n];
        } else if (n < 136) {
            base = bE[v * 8 + (n - 128)];
            wk = WE[k * 16 + v * 8 + (n - 128)];
        }
        float p = ln_b[k] * wk;
        p += __shfl_xor(p, 1);  p += __shfl_xor(p, 2);
        p += __shfl_xor(p, 4);  p += __shfl_xor(p, 8);
        p += __shfl_xor(p, 16); p += __shfl_xor(p, 32);
        __shared__ float partial[2];
        if ((t & 63) == 0) partial[t >> 6] = p;
        __syncthreads();
        if (t == 0) bcat[idx] = base + partial[0] + partial[1];
    }
}

// ---------------------------------------------------------------------------
// K1 (round-5 validated): fused LN + projection + softmax, register-A-frag.
// blockIdx: x = fixed row (256), y = b (2), z = variant v (2).
//  v=0: fix=i, k=r2 -> V_in + E_in softmax; v=1: fix=j, k=r1 -> V_out + E_out.
// Wave w owns k-rows [w*64, w*64+64). Lane (quad,ln_) normalizes row
// (w*64+mt*16+ln_), cols quad*8+kk*32 -> exactly its MFMA A-fragment data.
// Wv in LDS: granule slot (r,p) holds source granule p ^ (r&15).
// V-chunk GEMM done in two ntl-halves (acc[4][2]) to keep peak register
// pressure ~134 < 168-reg cap of launch_bounds(256,3).
// ---------------------------------------------------------------------------
__global__ __launch_bounds__(256, 3) void k1_ln_proj(
    const float* __restrict__ e, const float* __restrict__ ln_g,
    const float* __restrict__ ln_b, const float* __restrict__ mask,
    const short* __restrict__ Wcat2, const float* __restrict__ bcat,
    short* __restrict__ VinT, short* __restrict__ VoutT,
    short* __restrict__ Ain, short* __restrict__ AoutT) {
    (void)ln_g; (void)ln_b;           // folded into Wcat2/bcat by k0
    __shared__ short Wlds[144 * 128]; // 36,864 B, granule-swizzled
    __shared__ float maskb[256];
    __shared__ float redm[4][8];
    __shared__ float reds[4][8];

    const int tid = threadIdx.x;
    const int fix = blockIdx.x;
    const int b = blockIdx.y;
    const int v = blockIdx.z;
    const int estride = v ? 256 : 1;
    const size_t ebase = (size_t)b * 65536 + (size_t)fix * (v ? 1 : 256);
    const short* Wv = Wcat2 + v * 144 * 128;
    const float* bc = bcat + v * 144;
    short* Vdst = v ? VoutT : VinT;
    short* Adst = v ? AoutT : Ain;

    const int lane = tid & 63, w = tid >> 6;
    const int ln_ = lane & 15, quad = lane >> 4;

    // ---- stage Wv -> LDS (async, hides under LN's global loads) ----
#pragma unroll
    for (int it = 0; it < 9; ++it) {
        int gid = it * 256 + tid;          // 0..2303
        int r = gid >> 4, p = gid & 15;
        const short* src = Wv + (r * 16 + (p ^ (r & 15))) * 8;
        __builtin_amdgcn_global_load_lds(AS1(src), AS3(&Wlds[gid * 8]), 16, 0, 0);
    }

    maskb[tid] = mask[(size_t)b * 65536 + (v ? (size_t)tid * 256 + fix
                                             : (size_t)fix * 256 + tid)];

    // ---- LayerNorm straight into per-wave A fragments (no LDS) ----
    short8 a_frag[4][4];
#pragma unroll
    for (int mt = 0; mt < 4; ++mt) {
        int row = w * 64 + mt * 16 + ln_;
        const float* ep = e + (ebase + (size_t)row * estride) * 128 + quad * 8;
        float4 c0[4], c1[4];
        float s = 0.f, s2 = 0.f;
#pragma unroll
        for (int kk = 0; kk < 4; ++kk) {
            c0[kk] = *(const float4*)(ep + kk * 32);
            c1[kk] = *(const float4*)(ep + kk * 32 + 4);
            s += c0[kk].x + c0[kk].y + c0[kk].z + c0[kk].w +
                 c1[kk].x + c1[kk].y + c1[kk].z + c1[kk].w;
            s2 += c0[kk].x * c0[kk].x + c0[kk].y * c0[kk].y +
                  c0[kk].z * c0[kk].z + c0[kk].w * c0[kk].w +
                  c1[kk].x * c1[kk].x + c1[kk].y * c1[kk].y +
                  c1[kk].z * c1[kk].z + c1[kk].w * c1[kk].w;
        }
        // row-sum across the 4 quads (lane bits 4,5)
        s += __shfl_xor(s, 16); s2 += __shfl_xor(s2, 16);
        s += __shfl_xor(s, 32); s2 += __shfl_xor(s2, 32);
        float mean = s * 0.0078125f;
        float var = s2 * 0.0078125f - mean * mean;
        float rs = rsqrtf(var + 1e-5f);
#pragma unroll
        for (int kk = 0; kk < 4; ++kk) {
            short8 o;
            o[0] = f2bf((c0[kk].x - mean) * rs);
            o[1] = f2bf((c0[kk].y - mean) * rs);
            o[2] = f2bf((c0[kk].z - mean) * rs);
            o[3] = f2bf((c0[kk].w - mean) * rs);
            o[4] = f2bf((c1[kk].x - mean) * rs);
            o[5] = f2bf((c1[kk].y - mean) * rs);
            o[6] = f2bf((c1[kk].z - mean) * rs);
            o[7] = f2bf((c1[kk].w - mean) * rs);
            a_frag[mt][kk] = o;
        }
    }
    __syncthreads();   // Wv staged + maskb visible

    float vE[16];

    // ---- V chunks: wave w owns k-rows w*64..w*64+63 (4 m-subtiles) ----
#pragma unroll
    for (int chunk = 0; chunk < 2; ++chunk) {
#pragma unroll
        for (int half = 0; half < 2; ++half) {
            floatx4 acc[4][2] = {};
#pragma unroll
            for (int kk = 0; kk < 4; ++kk) {
                int ckb = kk * 4 + quad;
                short8 bq[2];
#pragma unroll
                for (int nl = 0; nl < 2; ++nl) {
                    int n = chunk * 64 + (half * 2 + nl) * 16 + ln_;
                    bq[nl] = *(const short8*)&Wlds[(n * 16 + (ckb ^ (n & 15))) * 8];
                }
#pragma unroll
                for (int mt = 0; mt < 4; ++mt)
#pragma unroll
                    for (int nl = 0; nl < 2; ++nl)
                        acc[mt][nl] = __builtin_amdgcn_mfma_f32_16x16x32_bf16(
                            a_frag[mt][kk], bq[nl], acc[mt][nl], 0, 0, 0);
            }
#pragma unroll
            for (int nl = 0; nl < 2; ++nl) {
                int ntl = half * 2 + nl;
                int c = chunk * 64 + ntl * 16 + ln_;
                float bias = bc[c];
                int d = c >> 3, hh = c & 7;
                size_t rowbase = (((size_t)(b * 8 + hh) * 256 + fix) * 16 + d) * 256;
#pragma unroll
                for (int mt = 0; mt < 4; ++mt) {
                    short4v o;
#pragma unroll
                    for (int r = 0; r < 4; ++r) o[r] = f2bf(acc[mt][nl][r] + bias);
                    *(short4v*)(Vdst + rowbase + w * 64 + mt * 16 + quad * 4) = o;
                }
            }
        }
    }

    // ---- E chunk: cols 128..143 (8 real + 8 pad) ----
    {
        floatx4 accE[4] = {};
#pragma unroll
        for (int kk = 0; kk < 4; ++kk) {
            int ckb = kk * 4 + quad;
            int n = 128 + ln_;
            short8 bq = *(const short8*)&Wlds[(n * 16 + (ckb ^ (n & 15))) * 8];
#pragma unroll
            for (int mt = 0; mt < 4; ++mt)
                accE[mt] = __builtin_amdgcn_mfma_f32_16x16x32_bf16(
                    a_frag[mt][kk], bq, accE[mt], 0, 0, 0);
        }
        float bias = bc[128 + ln_];
#pragma unroll
        for (int mt = 0; mt < 4; ++mt)
#pragma unroll
            for (int r = 0; r < 4; ++r) {
                int k = w * 64 + mt * 16 + quad * 4 + r;
                vE[mt * 4 + r] = accE[mt][r] + bias + maskb[k];
            }
    }

    // ---- softmax over the 16 k-values per (lane-col, wave) ----
    {
        float m = vE[0];
#pragma unroll
        for (int i = 1; i < 16; ++i) m = fmaxf(m, vE[i]);
        m = fmaxf(m, __shfl_xor(m, 16));
        m = fmaxf(m, __shfl_xor(m, 32));
        if (quad == 0 && ln_ < 8) redm[w][ln_] = m;
        __syncthreads();
        int hs = ln_ & 7;
        float bmax = fmaxf(fmaxf(redm[0][hs], redm[1][hs]),
                           fmaxf(redm[2][hs], redm[3][hs]));
        float p[16], s = 0.f;
#pragma unroll
        for (int i = 0; i < 16; ++i) { p[i] = __expf(vE[i] - bmax); s += p[i]; }
        s += __shfl_xor(s, 16);
        s += __shfl_xor(s, 32);
        if (quad == 0 && ln_ < 8) reds[w][ln_] = s;
        __syncthreads();
        float inv = 1.f / (reds[0][hs] + reds[1][hs] + reds[2][hs] + reds[3][hs]);
        if (ln_ < 8) {
            size_t rowbase = (size_t)(b * 8 + ln_) * 65536 + (size_t)fix * 256;
#pragma unroll
            for (int mt = 0; mt < 4; ++mt) {
                short4v o;
#pragma unroll
                for (int r = 0; r < 4; ++r) o[r] = f2bf(p[mt * 4 + r] * inv);
                *(short4v*)(Adst + rowbase + w * 64 + mt * 16 + quad * 4) = o;
            }
        }
    }
}

// ---------------------------------------------------------------------------
// K3 (round-14 validated): per (b,h,part): C[i,jd] = sum_k A[i,k] V[jd,k].
// 512 threads (8 waves), 256x128 tile, BK=64 x4, (512,4): 64 VGPR/64 AGPR,
// no spill, 2 blocks/CU x 8 waves = 16 waves/CU. LDS 49,152 B.
// grid (32 jd-tiles, 32 z). Wave w: m0=(w>>1)*64 (256-row A), n0=(w&1)*64.
// Epilogue: two 128-row halves through a 128x136 C buffer, cooperative
// line-complete stores.
// ---------------------------------------------------------------------------
__global__ __launch_bounds__(512, 4) void k3_einsum(const short* __restrict__ Ain,
                                                    const short* __restrict__ AoutT,
                                                    const short* __restrict__ VinT,
                                                    const short* __restrict__ VoutT,
                                                    short* __restrict__ VaP2) {
    __shared__ short AB[24576];  // 49,152 B (epilogue reuses first 34,816 B)
    const int tid = threadIdx.x, lane = tid & 63, w = tid >> 6;
    const int jd0 = blockIdx.x * 128;
    const int z = blockIdx.y;
    const int b = z >> 4, part = (z >> 3) & 1, h = z & 7;

    const short* Abase = (part ? AoutT : Ain) + ((size_t)(b * 8 + h)) * 65536;
    const short* Bbase = (part ? VoutT : VinT) + ((size_t)(b * 8 + h)) * 1048576 + (size_t)jd0 * 256;

    const int ln_ = lane & 15, quad = lane >> 4;
    const int m0 = (w >> 1) * 64, n0 = (w & 1) * 64;
    floatx4 acc[4][4] = {};

    for (int kt = 0; kt < 4; ++kt) {
        if (kt) __syncthreads();
        for (int it = 0; it < 6; ++it) {
            int cid = it * 512 + tid;             // 0..3071
            int isB = cid >> 11;                  // granules >=2048 are B
            int lc = isB ? (cid - 2048) : cid;
            int r = lc >> 3;                      // A: 0..255, B: 0..127
            int ck = (lc & 7) ^ (r & 7);
            const short* g = (isB ? Bbase : Abase) + r * 256 + kt * 64 + ck * 8;
            __builtin_amdgcn_global_load_lds(AS1(g), AS3(&AB[cid * 8]), 16, 0, 0);
        }
        __syncthreads();

#pragma unroll
        for (int kk = 0; kk < 2; ++kk) {
            int ckb = kk * 4 + quad;
            short8 aq[4], bq[4];
#pragma unroll
            for (int t = 0; t < 4; ++t) {
                int r = m0 + t * 16 + ln_;        // 0..255
                aq[t] = *(const short8*)&AB[(r * 8 + (ckb ^ (r & 7))) * 8];
            }
#pragma unroll
            for (int t = 0; t < 4; ++t) {
                int r = n0 + t * 16 + ln_;        // 0..127
                bq[t] = *(const short8*)&AB[(2048 + r * 8 + (ckb ^ (r & 7))) * 8];
            }
#pragma unroll
            for (int mt = 0; mt < 4; ++mt)
#pragma unroll
                for (int nt = 0; nt < 4; ++nt)
                    acc[mt][nt] = __builtin_amdgcn_mfma_f32_16x16x32_bf16(aq[mt], bq[nt], acc[mt][nt], 0, 0, 0);
        }
    }

    // ---- epilogue: two 128-row halves through a 128x136 C buffer ----
    const int ph = part * 8 + h;
    const int j0 = jd0 >> 4;
    __syncthreads();   // all AB K-loop reads done
#pragma unroll
    for (int mh = 0; mh < 2; ++mh) {
        if (mh) __syncthreads();    // previous half's stores done
        if ((m0 >> 7) == mh) {      // waves owning rows [mh*128, mh*128+128)
            int il0 = m0 & 127;
#pragma unroll
            for (int mt = 0; mt < 4; ++mt)
#pragma unroll
                for (int nt = 0; nt < 4; ++nt)
#pragma unroll
                    for (int r = 0; r < 4; ++r) {
                        int il = il0 + mt * 16 + quad * 4 + r;
                        int jd = n0 + nt * 16 + ln_;
                        AB[il * 136 + jd] = f2bf(acc[mt][nt][r]);
                    }
        }
        __syncthreads();            // C half staged
#pragma unroll
        for (int pp = 0; pp < 2; ++pp) {
            int pid = pp * 512 + tid;      // 0..1023
            int il = pid >> 3, jl = pid & 7;
            size_t m = ((size_t)b * 256 + mh * 128 + il) * 256 + j0 + jl;
            short8 v0 = *(const short8*)&AB[il * 136 + jl * 16];
            short8 v1 = *(const short8*)&AB[il * 136 + jl * 16 + 8];
            short* dst = VaP2 + ((size_t)ph * 131072 + m) * 16;
            *(short8*)dst = v0;
            *(short8*)(dst + 8) = v1;
        }
    }
}

// ---------------------------------------------------------------------------
// K4 (round-15): out[m][w] = sum_c A[m][c] * WOt2[cc][w][8] + bO[w].
// 512 threads (8 waves), 256-row tile, (512,4): 64 VGPR/64 AGPR split;
// VGPR side aq8+bq32+bo8+addr~10 <= 64, acc[2][8]=64 AGPR -> no spill.
// A_s 64 KB -> 2 blocks/CU -> 16 waves/CU (was 12). grid 512.
// Per-wave inner loop byte-identical to validated k4 (m0=w*32, same
// aq/bq/MFMA); staging decode widened one bit (m 0..255).
// Store discipline unchanged: each out row's 512 B = 8 consecutive
// nt-stores by one wave.
// ---------------------------------------------------------------------------
__global__ __launch_bounds__(512, 4) void k4_proj(const short* __restrict__ VaP2,
                                                  const short* __restrict__ WOt2,
                                                  const float* __restrict__ bO,
                                                  float* __restrict__ out) {
    __shared__ short A_s[32768];  // 64 KB
    const int tid = threadIdx.x, lane = tid & 63, w = tid >> 6;
    const size_t m0g = (size_t)blockIdx.x * 256;
    const int ln_ = lane & 15, quad = lane >> 4;
    const int m0 = w * 32;
    floatx4 acc[2][8] = {};

    for (int kt = 0; kt < 2; ++kt) {
        if (kt) __syncthreads();
        for (int it = 0; it < 8; ++it) {
            int cid = it * 512 + tid;               // 0..4095
            int p = cid >> 9, rm = cid & 511, half = rm >> 8, m = rm & 255;
            const short* g = VaP2 + ((size_t)(kt * 8 + p) * 131072 + m0g + m) * 16 + half * 8;
            __builtin_amdgcn_global_load_lds(AS1(g), AS3(&A_s[cid * 8]), 16, 0, 0);
        }
        __syncthreads();

#pragma unroll
        for (int kk = 0; kk < 4; ++kk) {
            int ckb = kk * 4 + quad;
            int p = ckb >> 1, hf = ckb & 1;
            short8 aq[2], bq[8];
#pragma unroll
            for (int mt = 0; mt < 2; ++mt) {
                int m = m0 + mt * 16 + ln_;         // 0..255
                aq[mt] = *(const short8*)&A_s[p * 4096 + hf * 2048 + m * 8];
            }
#pragma unroll
            for (int nt = 0; nt < 8; ++nt) {
                int wr = nt * 16 + ln_;
                bq[nt] = *(const short8*)(WOt2 + ((kt * 16 + ckb) * 128 + wr) * 8);
            }
#pragma unroll
            for (int mt = 0; mt < 2; ++mt)
#pragma unroll
                for (int nt = 0; nt < 8; ++nt)
                    acc[mt][nt] = __builtin_amdgcn_mfma_f32_16x16x32_bf16(aq[mt], bq[nt], acc[mt][nt], 0, 0, 0);
        }
    }

    float bo[8];
#pragma unroll
    for (int nt = 0; nt < 8; ++nt) bo[nt] = bO[nt * 16 + ln_];

#pragma unroll
    for (int mt = 0; mt < 2; ++mt)
#pragma unroll
        for (int r = 0; r < 4; ++r) {
            size_t mb = m0g + m0 + mt * 16 + quad * 4 + r;
#pragma unroll
            for (int nt = 0; nt < 8; ++nt)
                out[mb * 128 + nt * 16 + ln_] = acc[mt][nt][r] + bo[nt];
        }
}

// ---------------------------------------------------------------------------
extern "C" void kernel_launch(void* const* d_in, const int* in_sizes, int n_in,
                              void* d_out, int out_size, void* d_ws, size_t ws_size,
                              hipStream_t stream) {
    (void)in_sizes; (void)n_in; (void)out_size; (void)ws_size;
    const float* e    = (const float*)d_in[0];
    const float* mask = (const float*)d_in[1];
    const float* ln_g = (const float*)d_in[2];
    const float* ln_b = (const float*)d_in[3];
    const float* W_V  = (const float*)d_in[4];
    const float* b_V  = (const float*)d_in[5];
    const float* W_E  = (const float*)d_in[6];
    const float* b_E  = (const float*)d_in[7];
    const float* W_O  = (const float*)d_in[8];
    const float* b_O  = (const float*)d_in[9];
    float* out = (float*)d_out;

    char* ws = (char*)d_ws;
    short* VinT  = (short*)(ws + 0);           //  33,554,432 B
    short* VoutT = (short*)(ws + 33554432);    //  33,554,432 B
    short* Ain   = (short*)(ws + 67108864);    //   2,097,152 B
    short* AoutT = (short*)(ws + 69206016);    //   2,097,152 B
    short* VaP2  = (short*)(ws + 71303168);    //  67,108,864 B
    short* Wcat2 = (short*)(ws + 138412032);   //      73,728 B
    short* WOt2  = (short*)(ws + 138485760);   //      65,536 B
    float* bcat  = (float*)(ws + 138551296);   //       1,152 B

    k0_prep<<<608, 128, 0, stream>>>(W_V, W_E, W_O, ln_g, ln_b, Wcat2, WOt2,
                                     b_V, b_E, bcat);
    k1_ln_proj<<<dim3(256, 2, 2), 256, 0, stream>>>(e, ln_g, ln_b, mask, Wcat2,
                                                    bcat, VinT, VoutT, Ain, AoutT);
    k3_einsum<<<dim3(32, 32), 512, 0, stream>>>(Ain, AoutT, VinT, VoutT, VaP2);
    k4_proj<<<512, 512, 0, stream>>>(VaP2, WOt2, b_O, out);
}